// Round 9
// baseline (307.978 us; speedup 1.0000x reference)
//
#include <hip/hip_runtime.h>
#include <math.h>

#define T_STEPS 168
#define INP     19
#define HID     64
#define ROWS    8      // 8 batch rows/block -> grid 512 -> 2 blocks/CU (TLP)
#define NTH     512
#define HSTH    72     // h row stride (f16): 144 B, 16B-aligned
#define XSTH    40     // x row stride (f16): 80 B

typedef _Float16 half8   __attribute__((ext_vector_type(8)));
typedef float    floatx4 __attribute__((ext_vector_type(4)));

// 7-transcendental LSTM cell (was 10): one shared rcp for sigmoid(i)*tanh(g)
// and sigmoid(f); one for sigmoid(o)*tanh(c). g-gate weights carry the x2 of
// tanh; c-state kept in 2x scale (c2). Clamps bound the product dynamic range
// (exp-sum < 88 -> no inf; c2 clamp keeps e^{c2} finite over 168 steps).
__device__ __forceinline__ float lstm_cell(float zi, float zf, float zg2,
                                           float zo, float& c2) {
    zi  = fminf(fmaxf(zi,  -20.f), 20.f);
    zf  = fminf(fmaxf(zf,  -20.f), 20.f);
    zg2 = fminf(fmaxf(zg2, -40.f), 40.f);
    zo  = fminf(fmaxf(zo,  -20.f), 20.f);
    const float A = __expf(zi), F = __expf(zf), G = __expf(zg2), O = __expf(zo);
    const float pA = 1.f + A, pF = 1.f + F, pG = G + 1.f, mG = G - 1.f;
    const float d   = pA * pG;
    const float R   = __builtin_amdgcn_rcpf(d * pF);
    const float ft  = (F * d) * R;                  // sigmoid(zf)
    const float its = ((A * mG) * pF) * (R * 2.f);  // 2*sigmoid(zi)*tanh(zg)
    c2 = fmaf(ft, c2, its);
    c2 = fminf(fmaxf(c2, -35.f), 35.f);
    const float C2 = __expf(c2);                    // e^{2c}
    const float R2 = __builtin_amdgcn_rcpf((1.f + O) * (C2 + 1.f));
    return (O * (C2 - 1.f)) * R2;                   // sigmoid(zo)*tanh(c)
}

// r8 structure + ROWS=8/grid=512: 2 independent blocks/CU -> 4 waves/SIMD.
// MFMA M=16 tiles keep 8 zero rows (MFMA pipe only 17% busy - waste is free);
// C-tile halves redistributed via shfl_xor(32) so all 64 lanes activate 2
// valid cells (trans issue per SIMD conserved). waves_per_eu(4,4) pins the
// 128-VGPR budget (r3-r5 lesson: allocator chases LDS-permitted occupancy).
__global__ __launch_bounds__(NTH) __attribute__((amdgpu_waves_per_eu(4, 4)))
void lstm2_mfma4_kernel(const float* __restrict__ x,
                        const float* __restrict__ Wih0, const float* __restrict__ Whh0,
                        const float* __restrict__ bih0, const float* __restrict__ bhh0,
                        const float* __restrict__ Wih1, const float* __restrict__ Whh1,
                        const float* __restrict__ bih1, const float* __restrict__ bhh1,
                        const float* __restrict__ Wfc,  const float* __restrict__ bfc,
                        float* __restrict__ out)
{
    // 16 rows allocated (MFMA A-frag reads l16=0..15); rows 8-15 stay zero.
    __shared__ __align__(16) _Float16 xf [2][16][XSTH];
    __shared__ __align__(16) _Float16 h1f[2][16][HSTH];
    __shared__ __align__(16) _Float16 h2f[2][16][HSTH];
    __shared__ float hout[ROWS][HID];

    const int tid  = threadIdx.x;
    const int b0   = blockIdx.x * ROWS;
    const int wv   = tid >> 6;
    const int lane = tid & 63;
    const int quad = lane >> 4;
    const int l16  = lane & 15;
    const int kq   = quad * 8;
    const int lay  = wv >> 2;          // 0: layer1(t), 1: layer2(t-1)
    const int uq   = wv & 3;
    const int u    = uq * 16 + l16;
    const bool lowq = (quad < 2);
    // after redistribution: quad 0,1,2,3 own row-pairs {0,1},{4,5},{2,3},{6,7}
    const int rbase = ((lane & 16) ? 4 : 0) + ((lane & 32) ? 2 : 0);

    // ---- B-fragments (weights, f16) + bias, loaded ONCE.
    // g-gate (gi==2) rows scaled x2 (tanh folding). B[k][n]: n=l16, k=kq+e.
    half8 bfr[4][4];
    float bz[4];
#pragma unroll
    for (int gi = 0; gi < 4; ++gi) {
        const int gr = gi * 64 + u;
        const float ws = (gi == 2) ? 2.f : 1.f;
        if (lay == 0) {
            const float* wr = Wih0 + gr * INP;
#pragma unroll
            for (int e = 0; e < 8; ++e) {
                const int k = kq + e;
                bfr[gi][0][e] = (k < INP) ? (_Float16)(ws * wr[k]) : (_Float16)0.0f;
            }
            const float* hr = Whh0 + gr * HID;
#pragma unroll
            for (int e = 0; e < 8; ++e) {
                bfr[gi][1][e] = (_Float16)(ws * hr[kq + e]);
                bfr[gi][2][e] = (_Float16)(ws * hr[32 + kq + e]);
            }
            bfr[gi][3] = bfr[gi][2];   // unused on this path
            bz[gi] = ws * (bih0[gr] + bhh0[gr]);
        } else {
            const float* ir = Wih1 + gr * HID;
            const float* hr = Whh1 + gr * HID;
#pragma unroll
            for (int e = 0; e < 8; ++e) {
                bfr[gi][0][e] = (_Float16)(ws * ir[kq + e]);
                bfr[gi][1][e] = (_Float16)(ws * ir[32 + kq + e]);
                bfr[gi][2][e] = (_Float16)(ws * hr[kq + e]);
                bfr[gi][3][e] = (_Float16)(ws * hr[32 + kq + e]);
            }
            bz[gi] = ws * (bih1[gr] + bhh1[gr]);
        }
    }

    float cstA = 0.f, cstB = 0.f;      // 2x-scaled cell state, 2 cells/lane

    // ---- x staging constants (threads 0..151 stage one element/iter) ----
    int srr = 0, sii = 0;
    const float* xsrc = nullptr;
    if (tid < ROWS * INP) {
        srr = tid / INP; sii = tid - srr * INP;
        xsrc = x + ((size_t)(b0 + srr) * T_STEPS) * INP + sii;
    }

    // ---- init LDS: everything zero (rows 8-15 stay zero forever) ----
    for (int e = tid; e < 2 * 16 * XSTH; e += NTH) ((_Float16*)xf)[e] = (_Float16)0.f;
    for (int e = tid; e < 2 * 16 * HSTH; e += NTH) {
        ((_Float16*)h1f)[e] = (_Float16)0.f;
        ((_Float16*)h2f)[e] = (_Float16)0.f;
    }
    __syncthreads();
    float xregA = 0.f, xregB = 0.f;    // x(t+1), x(t+2) pipeline
    if (xsrc) {
        xf[0][srr][sii] = (_Float16)xsrc[0];
        xregA = xsrc[INP];                       // x(1)
        xregB = xsrc[2 * (size_t)INP];           // x(2)
    }
    __syncthreads();

    for (int t = 0; t <= T_STEPS; ++t) {
        // stage x(t+1) from reg (loaded 2 iters ago - no vm wait), refill pipe
        if (xsrc && (t + 1) < T_STEPS)
            xf[(t + 1) & 1][srr][sii] = (_Float16)xregA;
        float xnew = 0.f;
        if (xsrc) {
            const int tn = (t + 3 < T_STEPS) ? (t + 3) : (T_STEPS - 1);
            xnew = xsrc[(size_t)tn * INP];
        }

        const bool act = (lay == 0) ? (t < T_STEPS) : (t >= 1);
        if (act) {
            floatx4 acc[4];
#pragma unroll
            for (int gi = 0; gi < 4; ++gi)
                acc[gi] = (floatx4){bz[gi], bz[gi], bz[gi], bz[gi]};
            if (lay == 0) {
                const half8 ax = *(const half8*)&xf [t & 1][l16][kq];
                const half8 a0 = *(const half8*)&h1f[(t + 1) & 1][l16][kq];
                const half8 a1 = *(const half8*)&h1f[(t + 1) & 1][l16][32 + kq];
#pragma unroll
                for (int gi = 0; gi < 4; ++gi) {
                    acc[gi] = __builtin_amdgcn_mfma_f32_16x16x32_f16(ax, bfr[gi][0], acc[gi], 0, 0, 0);
                    acc[gi] = __builtin_amdgcn_mfma_f32_16x16x32_f16(a0, bfr[gi][1], acc[gi], 0, 0, 0);
                    acc[gi] = __builtin_amdgcn_mfma_f32_16x16x32_f16(a1, bfr[gi][2], acc[gi], 0, 0, 0);
                }
            } else {
                const half8 p0 = *(const half8*)&h1f[(t + 1) & 1][l16][kq];
                const half8 p1 = *(const half8*)&h1f[(t + 1) & 1][l16][32 + kq];
                const half8 q0 = *(const half8*)&h2f[t & 1][l16][kq];
                const half8 q1 = *(const half8*)&h2f[t & 1][l16][32 + kq];
#pragma unroll
                for (int gi = 0; gi < 4; ++gi) {
                    acc[gi] = __builtin_amdgcn_mfma_f32_16x16x32_f16(p0, bfr[gi][0], acc[gi], 0, 0, 0);
                    acc[gi] = __builtin_amdgcn_mfma_f32_16x16x32_f16(p1, bfr[gi][1], acc[gi], 0, 0, 0);
                    acc[gi] = __builtin_amdgcn_mfma_f32_16x16x32_f16(q0, bfr[gi][2], acc[gi], 0, 0, 0);
                    acc[gi] = __builtin_amdgcn_mfma_f32_16x16x32_f16(q1, bfr[gi][3], acc[gi], 0, 0, 0);
                }
            }
            // ---- redistribute: rows 0-7 live in quads 0,1 (4 cells/lane);
            //      ship half to quads 2,3 so every lane activates 2 cells ----
            float zA[4], zB[4];
#pragma unroll
            for (int gi = 0; gi < 4; ++gi) {
                const float sA = __shfl_xor(acc[gi][2], 32);
                const float sB = __shfl_xor(acc[gi][3], 32);
                zA[gi] = lowq ? acc[gi][0] : sA;
                zB[gi] = lowq ? acc[gi][1] : sB;
            }
            const float hA = lstm_cell(zA[0], zA[1], zA[2], zA[3], cstA);
            const float hB = lstm_cell(zB[0], zB[1], zB[2], zB[3], cstB);
            if (lay == 0) {
                h1f[t & 1][rbase][u]     = (_Float16)hA;       // h1(t)
                h1f[t & 1][rbase + 1][u] = (_Float16)hB;
            } else {
                h2f[(t + 1) & 1][rbase][u]     = (_Float16)hA; // h2(t-1)
                h2f[(t + 1) & 1][rbase + 1][u] = (_Float16)hB;
                if (t == T_STEPS) {
                    hout[rbase][u]     = hA;
                    hout[rbase + 1][u] = hB;
                }
            }
        }
        xregA = xregB; xregB = xnew;
        __syncthreads();   // single barrier: iter-t writes visible to iter t+1
    }

    // ---- FC epilogue: out[b] = h2(T-1)[b,:] . Wfc + bfc ----
    if (tid < ROWS) {
        float a = bfc[0];
        const float* hr = hout[tid];
#pragma unroll
        for (int k = 0; k < HID; ++k)
            a = fmaf(hr[k], Wfc[k], a);
        out[b0 + tid] = a;
    }
}

extern "C" void kernel_launch(void* const* d_in, const int* in_sizes, int n_in,
                              void* d_out, int out_size, void* d_ws, size_t ws_size,
                              hipStream_t stream) {
    const float* x    = (const float*)d_in[0];
    const float* Wih0 = (const float*)d_in[1];
    const float* Whh0 = (const float*)d_in[2];
    const float* bih0 = (const float*)d_in[3];
    const float* bhh0 = (const float*)d_in[4];
    const float* Wih1 = (const float*)d_in[5];
    const float* Whh1 = (const float*)d_in[6];
    const float* bih1 = (const float*)d_in[7];
    const float* bhh1 = (const float*)d_in[8];
    const float* Wfc  = (const float*)d_in[9];
    const float* bfc  = (const float*)d_in[10];
    float* out = (float*)d_out;

    const int B = in_sizes[0] / (T_STEPS * INP);   // 4096
    const int grid = B / ROWS;                     // 512 workgroups, 2 per CU

    lstm2_mfma4_kernel<<<dim3(grid), dim3(NTH), 0, stream>>>(
        x, Wih0, Whh0, bih0, bhh0, Wih1, Whh1, bih1, bhh1, Wfc, bfc, out);
}